// Round 7
// baseline (171.700 us; speedup 1.0000x reference)
//
#include <hip/hip_runtime.h>

// Detail_loss: loss = 0.25/(98*258*256) * sum_{n,h,w} ( |D[h][w+1]-D[h][w-1]| + |D[h+1][w]-D[h-1][w]| )
// where D[n,h,w] = sum_c (infer - ref)[n,c,h,w], zero outside [0,256)^2.
// (identical per-channel-pair conv kernels -> channel-sum first; conv linearity ->
// difference first; pad rows/cols contribute 0; scale folds the 0.5 coeff, the 3
// output channels, and the /(98*3*258*256) means.)
//
// R6 = R5 (async global_load_lds staging: 60 x 1KB rows/block, single drain,
// 2 blocks/CU = 120 KB in flight per CU) + XCD-CONTIGUOUS WORK SWIZZLE.
// R0-R5 all capped at ~1.7 TB/s fetch regardless of structure; last untested
// axis is request-stream locality: default round-robin block->XCD dispatch
// scatters adjacent strips across XCDs (no L2 halo reuse, interleaved DRAM
// streams). Swizzle gives XCD k the contiguous strip range [k*392, (k+1)*392):
// each XCD reads one ~19 MB slab of each tensor.

#define W 256
#define NIMG 98
#define CH_STRIDE 65536          // 256*256
#define TH 8
#define HALO (TH + 2)            // 10 rows incl. halo
#define NSTRIP 32                // 256 / TH
#define NBLK (NIMG * NSTRIP)     // 3136 = 8 * 392
#define NPER_XCD (NBLK / 8)      // 392
#define SCALE (0.25f / 6472704.0f)   // 0.25/(98*258*256)

__device__ __forceinline__ void async_copy16(const float* g, float* l) {
  // width=16: one instruction moves 64 lanes x 16 B = 1 KB (one image row).
  __builtin_amdgcn_global_load_lds(
      (const __attribute__((address_space(1))) void*)g,
      (__attribute__((address_space(3))) void*)l,
      16, 0, 0);
}

struct SmemT {
  float raw[6][HALO][W];   // 60 KB: slots 0-2 = x ch0-2, 3-5 = y ch0-2
  float Dsh[HALO][W];      // 10 KB: channel-summed difference rows
  float ws[4];
};

__device__ __forceinline__ float block_body(const float* __restrict__ x,
                                            const float* __restrict__ y,
                                            SmemT& sm) {
  const int tid = threadIdx.x;
  const int lane = tid & 63;
  const int wv   = tid >> 6;

  // XCD-contiguous swizzle: blocks with the same (blockIdx & 7) land on the
  // same XCD (round-robin dispatch); give them a contiguous strip range.
  const int b     = (blockIdx.x & 7) * NPER_XCD + (blockIdx.x >> 3);
  const int n     = b >> 5;          // image
  const int strip = b & 31;
  const int r0    = strip * TH;

  const float* xb = x + (size_t)n * 3 * CH_STRIDE;
  const float* yb = y + (size_t)n * 3 * CH_STRIDE;

  // ---- Phase 1: 60 async row loads, 15 per wave, hardware-queued (no VGPRs).
  #pragma unroll
  for (int i = 0; i < 15; ++i) {
    const int id = wv + 4 * i;       // 0..59, wave-uniform
    const int s  = id / HALO;        // tensor-channel slot 0..5
    const int lr = id % HALO;        // local halo row 0..9
    int g = r0 - 1 + lr;
    g = (g < 0) ? 0 : (g > 255 ? 255 : g);   // clamp; OOB masked to 0 in phase 2a
    const float* gp = ((s < 3) ? (xb + s * CH_STRIDE) : (yb + (s - 3) * CH_STRIDE))
                      + g * W + (lane << 2);
    async_copy16(gp, &sm.raw[s][lr][0]);
  }
  __syncthreads();   // single vmcnt drain for all 60 loads

  // ---- Phase 2a: thread = column w; channel-summed difference rows.
  const int w = tid;
  float d[HALO];
  #pragma unroll
  for (int lr = 0; lr < HALO; ++lr) {
    const int g = r0 - 1 + lr;       // block-uniform branch
    float v = 0.f;
    if (g >= 0 && g < 256) {
      v = (sm.raw[0][lr][w] - sm.raw[3][lr][w])
        + (sm.raw[1][lr][w] - sm.raw[4][lr][w])
        + (sm.raw[2][lr][w] - sm.raw[5][lr][w]);
    }
    d[lr] = v;
    sm.Dsh[lr][w] = v;
  }
  __syncthreads();

  // ---- Phase 2b: 8 strip rows; horizontal from LDS (stride-1), vertical from regs.
  float acc = 0.f;
  #pragma unroll
  for (int r = 0; r < TH; ++r) {
    const float* rp = sm.Dsh[r + 1];
    float left  = (w > 0)     ? rp[w - 1] : 0.f;   // image col -1 zero pad
    float right = (w < W - 1) ? rp[w + 1] : 0.f;   // image col 256 zero pad
    acc += fabsf(right - left) + fabsf(d[r + 2] - d[r]);
  }

  // ---- Block reduce.
  #pragma unroll
  for (int off = 32; off > 0; off >>= 1)
    acc += __shfl_down(acc, off, 64);
  if (lane == 0) sm.ws[wv] = acc;
  __syncthreads();
  return sm.ws[0] + sm.ws[1] + sm.ws[2] + sm.ws[3];
}

__global__ __launch_bounds__(256) void detail_stage1(
    const float* __restrict__ x, const float* __restrict__ y,
    float* __restrict__ partial) {
  __shared__ SmemT sm;
  float s = block_body(x, y, sm);
  if (threadIdx.x == 0) partial[blockIdx.x] = s;
}

__global__ __launch_bounds__(256) void detail_stage1_atomic(
    const float* __restrict__ x, const float* __restrict__ y,
    float* __restrict__ out) {
  __shared__ SmemT sm;
  float s = block_body(x, y, sm);
  if (threadIdx.x == 0) atomicAdd(out, s * SCALE);
}

__global__ __launch_bounds__(256) void detail_stage2(
    const float* __restrict__ partial, float* __restrict__ out) {
  float acc = 0.f;
  for (int i = threadIdx.x; i < NBLK; i += 256) acc += partial[i];
  #pragma unroll
  for (int off = 32; off > 0; off >>= 1)
    acc += __shfl_down(acc, off, 64);
  __shared__ float ws[4];
  if ((threadIdx.x & 63) == 0) ws[threadIdx.x >> 6] = acc;
  __syncthreads();
  if (threadIdx.x == 0) out[0] = (ws[0] + ws[1] + ws[2] + ws[3]) * SCALE;
}

extern "C" void kernel_launch(void* const* d_in, const int* in_sizes, int n_in,
                              void* d_out, int out_size, void* d_ws, size_t ws_size,
                              hipStream_t stream) {
  const float* infer = (const float*)d_in[0];
  const float* ref   = (const float*)d_in[1];
  float* out = (float*)d_out;

  if (ws_size >= NBLK * sizeof(float)) {
    float* partial = (float*)d_ws;
    detail_stage1<<<NBLK, 256, 0, stream>>>(infer, ref, partial);
    detail_stage2<<<1, 256, 0, stream>>>(partial, out);
  } else {
    hipMemsetAsync(out, 0, sizeof(float), stream);
    detail_stage1_atomic<<<NBLK, 256, 0, stream>>>(infer, ref, out);
  }
}